// Round 3
// baseline (1131.043 us; speedup 1.0000x reference)
//
#include <hip/hip_runtime.h>

// Problem constants
#define B_   128
#define T_   512
#define EMB_ 128
#define H_   128
#define NL_  9
#define MT_  65536  // B*T

typedef __attribute__((ext_vector_type(8))) short short8v;
typedef __attribute__((ext_vector_type(4))) float float4v;

__device__ inline unsigned short f2bf(float f){
  unsigned u = __float_as_uint(f);
  u += 0x7FFFu + ((u >> 16) & 1u);          // round-to-nearest-even
  return (unsigned short)(u >> 16);
}
__device__ inline float bf2f(unsigned short s){
  return __uint_as_float(((unsigned)s) << 16);
}
__device__ inline float sigm(float x){ return 1.f / (1.f + __expf(-x)); }
__device__ inline float tanh_(float x){ return 2.f / (1.f + __expf(-2.f * x)) - 1.f; }

// ---------------------------------------------------------------- K0: weight prep
// Wall[dir][n(512)][k(256)] bf16 : k<128 -> Whh[n][k], k>=128 -> Wih[n][k-128]
// biasc[dir][n] = bih[n]+bhh[n]
__global__ void k0_prep(const float* __restrict__ Wihf, const float* __restrict__ Whhf,
                        const float* __restrict__ bihf, const float* __restrict__ bhhf,
                        const float* __restrict__ Wihb, const float* __restrict__ Whhb,
                        const float* __restrict__ bihb, const float* __restrict__ bhhb,
                        unsigned short* __restrict__ Wall, float* __restrict__ biasc){
  int blk = blockIdx.x;            // 0..1023
  int dir = blk >> 9;
  int n   = blk & 511;
  int k   = threadIdx.x;           // 0..255
  const float* Wih = dir ? Wihb : Wihf;
  const float* Whh = dir ? Whhb : Whhf;
  float v = (k < 128) ? Whh[n * H_ + k] : Wih[n * EMB_ + (k - 128)];
  Wall[((long)(dir * 512 + n)) * 256 + k] = f2bf(v);
  if (k == 0){
    const float* bi = dir ? bihb : bihf;
    const float* bh = dir ? bhhb : bhhf;
    biasc[dir * 512 + n] = bi[n] + bh[n];
  }
}

// ---------------------------------------------------------------- K1: embedding gather -> bf16
__global__ void k1_embed(const int* __restrict__ chars, const float* __restrict__ emb,
                         unsigned short* __restrict__ x){
  int i = blockIdx.x * blockDim.x + threadIdx.x;  // 2,097,152 total (each does 4 elems)
  int m = i >> 5, q = i & 31;
  int c = chars[m];
  const float4* e4 = (const float4*)(emb + (long)c * EMB_);
  float4 v = e4[q];
  ushort4 o;
  o.x = f2bf(v.x); o.y = f2bf(v.y); o.z = f2bf(v.z); o.w = f2bf(v.w);
  *(ushort4*)(x + (long)m * EMB_ + q * 4) = o;
}

// ---------------------------------------------------------------- K3: fused BiLSTM scan (MFMA)
// 16 blocks: dir = blk>>3, batch rows [b0, b0+16). 512 threads = 8 waves.
// Wave w owns gate cols {g*128 + w*16 + r} for g = i,f,g,o -> each lane holds
// i,f,g,o for its 4 (m, j) pairs in registers; c-state register-resident.
__global__ __launch_bounds__(512, 2) void k3_fused(
    const unsigned short* __restrict__ x,     // [B][T][128] bf16
    const unsigned short* __restrict__ Wall,  // [2][512][256] bf16
    const float* __restrict__ biasc,          // [2][512]
    unsigned short* __restrict__ hs)          // [2][B*T][128] bf16
{
  const int blk = blockIdx.x;        // 0..15
  const int dir = blk >> 3;
  const int b0  = (blk & 7) * 16;
  const int tid = threadIdx.x;
  const int w   = tid >> 6;          // wave 0..7
  const int l   = tid & 63;
  const int r   = l & 15;
  const int q   = l >> 4;
  const int jcol = w * 16 + r;       // hidden index j owned by this lane

  __shared__ unsigned short hA[2][2048];        // [buf][kf(4)][kq(4)][m(16)][e(8)]
  __shared__ unsigned short hbuf[8][16][128];   // output ring (8 steps)

  // ---- B fragments in registers: 4 gate subtiles x 8 K-slices
  short8v Bf[4][8];
  #pragma unroll
  for (int g = 0; g < 4; g++){
    const unsigned short* wp = Wall + ((long)(dir * 512 + g * 128 + jcol)) * 256 + q * 8;
    #pragma unroll
    for (int kf = 0; kf < 8; kf++)
      Bf[g][kf] = *(const short8v*)(wp + kf * 32);
  }
  float bias[4];
  #pragma unroll
  for (int g = 0; g < 4; g++) bias[g] = biasc[dir * 512 + g * 128 + jcol];

  // zero hA buffer 0 (h_init = 0)
  for (int i = tid; i < 2048; i += 512) hA[0][i] = 0;

  float cc[4] = {0.f, 0.f, 0.f, 0.f};
  const int hAoff = (jcol >> 5) * 512 + ((jcol & 31) >> 3) * 128 + (jcol & 7);

  // prefetch x fragments for step 0
  short8v xnxt[4];
  {
    int t0 = dir ? (T_ - 1) : 0;
    #pragma unroll
    for (int kf = 0; kf < 4; kf++)
      xnxt[kf] = *(const short8v*)(x + ((long)(b0 + r) * T_ + t0) * EMB_ + kf * 32 + q * 8);
  }
  __syncthreads();

  for (int s = 0; s < T_; s++){
    const int p = s & 1;
    short8v xcur[4];
    #pragma unroll
    for (int kf = 0; kf < 4; kf++) xcur[kf] = xnxt[kf];
    // prefetch next step's x (full step of latency cover)
    {
      int sn = (s + 1 < T_) ? s + 1 : s;
      int tn = dir ? (T_ - 1 - sn) : sn;
      #pragma unroll
      for (int kf = 0; kf < 4; kf++)
        xnxt[kf] = *(const short8v*)(x + ((long)(b0 + r) * T_ + tn) * EMB_ + kf * 32 + q * 8);
    }

    // ---- MFMA: gates = [h | x] @ Wall^T
    float4v acc[4];
    #pragma unroll
    for (int g = 0; g < 4; g++){ float4v z = {0.f,0.f,0.f,0.f}; acc[g] = z; }
    #pragma unroll
    for (int kf = 0; kf < 4; kf++){
      short8v af = *(const short8v*)&hA[p][(kf * 4 + q) * 128 + r * 8];
      #pragma unroll
      for (int g = 0; g < 4; g++)
        acc[g] = __builtin_amdgcn_mfma_f32_16x16x32_bf16(af, Bf[g][kf], acc[g], 0, 0, 0);
    }
    #pragma unroll
    for (int kf = 0; kf < 4; kf++){
      #pragma unroll
      for (int g = 0; g < 4; g++)
        acc[g] = __builtin_amdgcn_mfma_f32_16x16x32_bf16(xcur[kf], Bf[g][kf + 4], acc[g], 0, 0, 0);
    }

    // ---- gate nonlinearities + state update (all register-resident)
    #pragma unroll
    for (int reg = 0; reg < 4; reg++){
      int m = q * 4 + reg;
      float iv = sigm(acc[0][reg] + bias[0]);
      float fv = sigm(acc[1][reg] + bias[1]);
      float gg = tanh_(acc[2][reg] + bias[2]);
      float ov = sigm(acc[3][reg] + bias[3]);
      cc[reg] = fv * cc[reg] + iv * gg;
      float hv = ov * tanh_(cc[reg]);
      unsigned short hb = f2bf(hv);
      hA[p ^ 1][hAoff + m * 8] = hb;          // A-fragment for next step
      hbuf[s & 7][m][jcol] = hb;              // output ring
    }
    __syncthreads();

    // ---- coalesced flush of 8 steps of h
    if ((s & 7) == 7){
      #pragma unroll
      for (int mr = 0; mr < 4; mr++){
        int u  = tid + mr * 512;              // 0..2047 units of 8 elems
        int j8 = u & 15, mm = (u >> 4) & 15, ii = u >> 8;
        int sg = s - 7 + ii;
        int tg = dir ? (T_ - 1 - sg) : sg;
        short8v v = *(const short8v*)&hbuf[ii][mm][j8 * 8];
        *(short8v*)(hs + ((long)dir * MT_ + (long)(b0 + mm) * T_ + tg) * H_ + j8 * 8) = v;
      }
      __syncthreads();
    }
  }
}

// ---------------------------------------------------------------- K4: emissions = [hf,hb] @ Wout^T + bout
#define HSTR 264
__global__ __launch_bounds__(512) void k4_emis(const unsigned short* __restrict__ hs,
                                               const float* __restrict__ Wout,
                                               const float* __restrict__ bout,
                                               float* __restrict__ em){
  __shared__ float hcat[64 * HSTR];
  __shared__ float wo[NL_ * 256];
  int tid = threadIdx.x;
  int m0 = blockIdx.x * 64;
  const unsigned short* hf = hs;
  const unsigned short* hb = hs + (long)MT_ * H_;
  #pragma unroll
  for (int it = 0; it < 8; it++){
    int flat = it * 2048 + tid * 4;       // over 64*256 = 16384 elements
    int r = flat >> 8, u = flat & 255;
    const unsigned short* src = (u < 128) ? (hf + (long)(m0 + r) * H_ + u)
                                          : (hb + (long)(m0 + r) * H_ + (u - 128));
    ushort4 v = *(const ushort4*)src;
    hcat[r * HSTR + u]     = bf2f(v.x);
    hcat[r * HSTR + u + 1] = bf2f(v.y);
    hcat[r * HSTR + u + 2] = bf2f(v.z);
    hcat[r * HSTR + u + 3] = bf2f(v.w);
  }
  for (int f = tid; f < NL_ * 256; f += 512) wo[f] = Wout[f];
  __syncthreads();
  #pragma unroll
  for (int half = 0; half < 2; half++){
    int idx = half * 512 + tid;
    if (idx < 64 * NL_){
      int r = idx / NL_, lbl = idx % NL_;
      float acc = bout[lbl];
      #pragma unroll 8
      for (int u = 0; u < 256; u++)
        acc = fmaf(hcat[r * HSTR + u], wo[lbl * 256 + u], acc);
      em[(long)(m0 + r) * NL_ + lbl] = acc;
    }
  }
}

// ---------------------------------------------------------------- K5: CRF NLL per sequence
__global__ void k5_crf(const float* __restrict__ em, const int* __restrict__ chars,
                       const int* __restrict__ labels, const float* __restrict__ startv,
                       const float* __restrict__ endv, const float* __restrict__ trans,
                       float* __restrict__ partial){
  int b = blockIdx.x, lane = threadIdx.x;   // 64 threads (1 wave)
  const int* lab = labels + b * T_;
  const int* ch  = chars + b * T_;
  const float* e = em + (long)b * T_ * NL_;
  // --- score (parallel over t) ---
  float sc = 0.f; int cnt = 0;
  for (int t = lane; t < T_; t += 64){
    int m = (ch[t] != 0);
    cnt += m;
    if (m){
      sc += e[t * NL_ + lab[t]];
      if (t > 0) sc += trans[lab[t - 1] * NL_ + lab[t]];
    }
  }
  #pragma unroll
  for (int off = 32; off; off >>= 1){
    sc  += __shfl_down(sc, off);
    cnt += __shfl_down(cnt, off);
  }
  sc  = __shfl(sc, 0);
  cnt = __shfl(cnt, 0);
  if (cnt < 1) cnt = 1;
  // --- forward algorithm: lanes 0..8 hold alpha; emissions prefetched 1 step ahead ---
  int jl = (lane < NL_) ? lane : 0;
  float tcol[NL_];
  #pragma unroll
  for (int i = 0; i < NL_; i++) tcol[i] = trans[i * NL_ + jl];
  float alpha = (lane < NL_) ? (startv[jl] + e[jl]) : -1e30f;
  float evn = (lane < NL_) ? e[NL_ + jl] : 0.f;
  int   mn  = (ch[1] != 0);
  for (int t = 1; t < T_; t++){
    float ev = evn; int m = mn;
    int t2 = (t + 1 < T_) ? t + 1 : t;
    evn = (lane < NL_) ? e[t2 * NL_ + jl] : 0.f;
    mn  = (ch[t2] != 0);
    float vv[NL_]; float mx = -1e30f;
    #pragma unroll
    for (int i = 0; i < NL_; i++){
      vv[i] = __shfl(alpha, i) + tcol[i];
      mx = fmaxf(mx, vv[i]);
    }
    float ssum = 0.f;
    #pragma unroll
    for (int i = 0; i < NL_; i++) ssum += __expf(vv[i] - mx);
    float nxt = mx + __logf(ssum) + ev;
    if (m && lane < NL_) alpha = nxt;
  }
  float av = (lane < NL_) ? (alpha + endv[jl]) : -1e30f;
  float mx = av;
  #pragma unroll
  for (int off = 8; off; off >>= 1) mx = fmaxf(mx, __shfl_down(mx, off));
  mx = __shfl(mx, 0);
  float ex = (lane < NL_) ? __expf(av - mx) : 0.f;
  #pragma unroll
  for (int off = 8; off; off >>= 1) ex += __shfl_down(ex, off);
  if (lane == 0){
    float logZ = mx + __logf(ex);
    float score = sc + startv[lab[0]] + endv[lab[cnt - 1]];
    partial[b] = logZ - score;
  }
}

// ---------------------------------------------------------------- K6: deterministic final reduce
__global__ void k6_reduce(const float* __restrict__ partial, float* __restrict__ out){
  int lane = threadIdx.x;  // 128 threads
  float v = partial[lane];
  #pragma unroll
  for (int off = 32; off; off >>= 1) v += __shfl_down(v, off);
  __shared__ float tmp[2];
  if ((lane & 63) == 0) tmp[lane >> 6] = v;
  __syncthreads();
  if (lane == 0) out[0] = tmp[0] + tmp[1];
}

// ---------------------------------------------------------------- launch
extern "C" void kernel_launch(void* const* d_in, const int* in_sizes, int n_in,
                              void* d_out, int out_size, void* d_ws, size_t ws_size,
                              hipStream_t stream){
  const int*   chars  = (const int*)d_in[0];
  const int*   labels = (const int*)d_in[1];
  const float* emb    = (const float*)d_in[2];
  const float* Wihf   = (const float*)d_in[3];
  const float* Whhf   = (const float*)d_in[4];
  const float* bihf   = (const float*)d_in[5];
  const float* bhhf   = (const float*)d_in[6];
  const float* Wihb   = (const float*)d_in[7];
  const float* Whhb   = (const float*)d_in[8];
  const float* bihb   = (const float*)d_in[9];
  const float* bhhb   = (const float*)d_in[10];
  const float* Wout   = (const float*)d_in[11];
  const float* bout   = (const float*)d_in[12];
  const float* startv = (const float*)d_in[13];
  const float* endv   = (const float*)d_in[14];
  const float* trans  = (const float*)d_in[15];

  char* ws = (char*)d_ws;
  unsigned short* x     = (unsigned short*)(ws);                   // 16,777,216 B
  unsigned short* Wall  = (unsigned short*)(ws + 16777216);        //    524,288 B
  float*          biasc = (float*)         (ws + 17301504);        //      4,096 B
  unsigned short* hs    = (unsigned short*)(ws + 17305600);        //  33,554,432 B
  float*          em    = (float*)         (ws + 50860032);        //   2,359,296 B
  float*          part  = (float*)         (ws + 53219328);        //        512 B

  hipLaunchKernelGGL(k0_prep,  dim3(1024), dim3(256), 0, stream,
                     Wihf, Whhf, bihf, bhhf, Wihb, Whhb, bihb, bhhb, Wall, biasc);
  hipLaunchKernelGGL(k1_embed, dim3(8192), dim3(256), 0, stream, chars, emb, x);
  hipLaunchKernelGGL(k3_fused, dim3(16),   dim3(512), 0, stream, x, Wall, biasc, hs);
  hipLaunchKernelGGL(k4_emis,  dim3(1024), dim3(512), 0, stream, hs, Wout, bout, em);
  hipLaunchKernelGGL(k5_crf,   dim3(128),  dim3(64),  0, stream,
                     em, chars, labels, startv, endv, trans, part);
  hipLaunchKernelGGL(k6_reduce, dim3(1),   dim3(128), 0, stream, part, (float*)d_out);
}